// Round 4
// baseline (355.920 us; speedup 1.0000x reference)
//
#include <hip/hip_runtime.h>

#define NTOT 65472
#define NPAD 65536
#define NIMG 4
#define PRE_NMS 1000
#define POST_NMS 300

typedef unsigned long long u64;

// ---------------------------------------------------------------------------
// Kernel 1: decode. One thread per (image, padded anchor).
// Computes per-anchor max score/label (class 0 masked), delta-decodes box,
// clips, validity; writes decoded box, label, and 64-bit sort key.
// key = (~orderable(score) << 32) | anchor_idx  -> ascending = score desc, idx asc
// ---------------------------------------------------------------------------
__global__ __launch_bounds__(256) void k_decode(
    const float* __restrict__ b0, const float* __restrict__ s0, const float* __restrict__ r0,
    const float* __restrict__ b1, const float* __restrict__ s1, const float* __restrict__ r1,
    const float* __restrict__ b2, const float* __restrict__ s2, const float* __restrict__ r2,
    const float* __restrict__ b3, const float* __restrict__ s3, const float* __restrict__ r3,
    const float* __restrict__ b4, const float* __restrict__ s4, const float* __restrict__ r4,
    float* __restrict__ dec_boxes, int* __restrict__ labels, u64* __restrict__ keys)
{
    int gid = blockIdx.x * 256 + threadIdx.x;   // 0 .. 4*65536
    int img = gid >> 16;
    int a   = gid & 0xFFFF;
    if (a >= NTOT) { keys[gid] = ~0ull; return; }

    const float *bp, *sp, *rp; int la, nl;
    if (a < 49152)      { bp=b0; sp=s0; rp=r0; la=a;        nl=49152; }
    else if (a < 61440) { bp=b1; sp=s1; rp=r1; la=a-49152;  nl=12288; }
    else if (a < 64512) { bp=b2; sp=s2; rp=r2; la=a-61440;  nl=3072;  }
    else if (a < 65280) { bp=b3; sp=s3; rp=r3; la=a-64512;  nl=768;   }
    else                { bp=b4; sp=s4; rp=r4; la=a-65280;  nl=192;   }

    size_t row = (size_t)img * nl + la;

    // max/argmax over classes 1..79 (class 0 = background, masked to -inf).
    // strict '>' keeps first occurrence -> matches jnp.argmax.
    const float4* s4v = (const float4*)(sp + row * 80);
    float best; int lab;
    {
        float4 v = s4v[0];
        best = v.y; lab = 1;
        if (v.z > best) { best = v.z; lab = 2; }
        if (v.w > best) { best = v.w; lab = 3; }
    }
#pragma unroll
    for (int q = 1; q < 20; q++) {
        float4 v = s4v[q];
        int c = q * 4;
        if (v.x > best) { best = v.x; lab = c;     }
        if (v.y > best) { best = v.y; lab = c + 1; }
        if (v.z > best) { best = v.z; lab = c + 2; }
        if (v.w > best) { best = v.w; lab = c + 3; }
    }

    float4 bx = ((const float4*)bp)[row];
    float4 rg = ((const float4*)rp)[row];
    float x1 = bx.x, y1 = bx.y, x2 = bx.z, y2 = bx.w;
    float w = x2 - x1, h = y2 - y1;
    float cx = x1 + 0.5f * w, cy = y1 + 0.5f * h;
    float dx = rg.x * 0.1f, dy = rg.y * 0.1f, dw = rg.z * 0.2f, dh = rg.w * 0.2f;
    float pcx = dx * w + cx, pcy = dy * h + cy;
    float pw = expf(dw) * w, ph = expf(dh) * h;
    float nx1 = pcx - 0.5f * pw, ny1 = pcy - 0.5f * ph;
    float nx2 = pcx + 0.5f * pw, ny2 = pcy + 0.5f * ph;
    nx1 = fminf(fmaxf(nx1, 0.0f), 1024.0f);
    ny1 = fminf(fmaxf(ny1, 0.0f), 1024.0f);
    nx2 = fminf(fmaxf(nx2, 0.0f), 1024.0f);
    ny2 = fminf(fmaxf(ny2, 0.0f), 1024.0f);
    float wc = nx2 - nx1, hc = ny2 - ny1;
    bool valid = (best > 0.05f) && (wc >= 2.0f) && (hc >= 2.0f);
    float ns = valid ? best : -1.0f;

    size_t gi = (size_t)img * NTOT + a;
    ((float4*)dec_boxes)[gi] = make_float4(nx1, ny1, nx2, ny2);
    labels[gi] = lab;

    unsigned u = __float_as_uint(ns);
    unsigned ord = (u & 0x80000000u) ? ~u : (u | 0x80000000u);
    unsigned d = ~ord;
    keys[gid] = ((u64)d << 32) | (unsigned)a;
}

// ---------------------------------------------------------------------------
// Kernel 2: per-1024-chunk bitonic sort (ascending) in LDS.
// ---------------------------------------------------------------------------
__global__ __launch_bounds__(256) void k_chunksort(u64* __restrict__ keys)
{
    __shared__ u64 s[1024];
    u64* base = keys + (size_t)blockIdx.x * 1024;
    for (int i = threadIdx.x; i < 1024; i += 256) s[i] = base[i];
    __syncthreads();
    for (int k = 2; k <= 1024; k <<= 1) {
        for (int j = k >> 1; j > 0; j >>= 1) {
            for (int t = threadIdx.x; t < 1024; t += 256) {
                int l = t ^ j;
                if (l > t) {
                    u64 x = s[t], y = s[l];
                    bool up = (t & k) == 0;
                    if (up ? (x > y) : (x < y)) { s[t] = y; s[l] = x; }
                }
            }
            __syncthreads();
        }
    }
    for (int i = threadIdx.x; i < 1024; i += 256) base[i] = s[i];
}

// ---------------------------------------------------------------------------
// Kernel 3: merge two sorted 1024-lists, keep smallest (best) 1024, sorted.
// grid = NIMG * nOut blocks.
// ---------------------------------------------------------------------------
__global__ __launch_bounds__(256) void k_merge(const u64* __restrict__ in, u64* __restrict__ out,
                                               int inStride, int outStride, int nOut)
{
    __shared__ u64 s[2048];
    int img = blockIdx.x / nOut;
    int p   = blockIdx.x % nOut;
    const u64* a = in + (size_t)img * inStride + (size_t)(2 * p) * 1024;
    for (int i = threadIdx.x; i < 1024; i += 256) s[i] = a[i];
    for (int i = threadIdx.x; i < 1024; i += 256) s[1024 + i] = a[1024 + (1023 - i)];
    __syncthreads();
    // first bitonic-merge stage: min into lower half
    for (int i = threadIdx.x; i < 1024; i += 256) {
        u64 x = s[i], y = s[i + 1024];
        s[i] = (x < y) ? x : y;
    }
    __syncthreads();
    // finish merging the (bitonic) lower half ascending
    for (int j = 512; j > 0; j >>= 1) {
        for (int t = threadIdx.x; t < 1024; t += 256) {
            int l = t ^ j;
            if (l > t) {
                u64 x = s[t], y = s[l];
                if (x > y) { s[t] = y; s[l] = x; }
            }
        }
        __syncthreads();
    }
    u64* o = out + (size_t)img * outStride + (size_t)p * 1024;
    for (int i = threadIdx.x; i < 1024; i += 256) o[i] = s[i];
}

// ---------------------------------------------------------------------------
// Kernel 4: gather top-1000 (sorted) boxes/scores/labels.
// ---------------------------------------------------------------------------
__global__ __launch_bounds__(256) void k_gather(const u64* __restrict__ keys,
                                                const float* __restrict__ dec_boxes,
                                                const int* __restrict__ labels,
                                                float* __restrict__ sel_boxes,
                                                float* __restrict__ sel_scores,
                                                int* __restrict__ sel_labels)
{
    int img = blockIdx.x;
    const u64* list = keys + (size_t)img * NPAD;
    for (int r = threadIdx.x; r < PRE_NMS; r += 256) {
        u64 k = list[r];
        unsigned d = (unsigned)(k >> 32);
        unsigned idx = (unsigned)(k & 0xFFFFFFFFu);
        unsigned ord = ~d;
        unsigned u = (ord & 0x80000000u) ? (ord ^ 0x80000000u) : ~ord;
        float sc = __uint_as_float(u);
        size_t gi = (size_t)img * NTOT + idx;
        ((float4*)sel_boxes)[img * PRE_NMS + r] = ((const float4*)dec_boxes)[gi];
        sel_scores[img * PRE_NMS + r] = sc;
        sel_labels[img * PRE_NMS + r] = labels[gi];
    }
}

// ---------------------------------------------------------------------------
// Kernel 5: IoU suppression bitmask. Thread = (img, row, word); 64 cols/word.
// bit j set iff IoU(row, j) > 0.5 && j > row.
// ---------------------------------------------------------------------------
__global__ __launch_bounds__(256) void k_mask(const float* __restrict__ sel_boxes,
                                              u64* __restrict__ mask)
{
    int t = blockIdx.x * 256 + threadIdx.x;   // 4*1000*16 = 64000
    int img = t / 16000;
    int rem = t % 16000;
    int row = rem / 16;
    int w   = rem % 16;
    float4 br = ((const float4*)sel_boxes)[img * PRE_NMS + row];
    float ax1 = br.x, ay1 = br.y, ax2 = br.z, ay2 = br.w;
    float aarea = (ax2 - ax1) * (ay2 - ay1);
    u64 bits = 0;
    int j0 = w * 64;
    for (int jj = 0; jj < 64; jj++) {
        int j = j0 + jj;
        if (j >= PRE_NMS || j <= row) continue;
        float4 bb = ((const float4*)sel_boxes)[img * PRE_NMS + j];
        float ix1 = fmaxf(ax1, bb.x), iy1 = fmaxf(ay1, bb.y);
        float ix2 = fminf(ax2, bb.z), iy2 = fminf(ay2, bb.w);
        float iw = fmaxf(ix2 - ix1, 0.0f), ih = fmaxf(iy2 - iy1, 0.0f);
        float inter = iw * ih;
        float barea = (bb.z - bb.x) * (bb.w - bb.y);
        float uni = fmaxf(aarea + barea - inter, 1e-6f);
        if (inter / uni > 0.5f) bits |= 1ull << jj;
    }
    mask[((size_t)img * PRE_NMS + row) * 16 + w] = bits;
}

// ---------------------------------------------------------------------------
// Kernel 6: sequential sweep (wave 0; 16 lanes own 16 keep-words) + output.
// Mask staged into LDS in two 64000B halves (stays under 64KB static LDS).
// ---------------------------------------------------------------------------
__global__ __launch_bounds__(256) void k_sweep(const u64* __restrict__ mask,
                                               const float* __restrict__ sel_boxes,
                                               const float* __restrict__ sel_scores,
                                               const int* __restrict__ sel_labels,
                                               float* __restrict__ out)
{
    __shared__ u64 mlds[500 * 16];
    __shared__ u64 keepw[16];
    __shared__ int pcnt[17];
    int img = blockIdx.x;
    int tid = threadIdx.x;
    const u64* mrow = mask + (size_t)img * PRE_NMS * 16;

    // stage rows 0..499
    for (int i = tid; i < 8000; i += 256) mlds[i] = mrow[i];
    __syncthreads();

    u64 kw = 0;
    if (tid < 64) {
        int lane = tid;
        if (lane < 16) {
            for (int s = 0; s < 64; s++) {
                int slot = lane * 64 + s;
                float sc = (slot < PRE_NMS) ? sel_scores[img * PRE_NMS + slot] : -1.0f;
                if (sc > 0.05f) kw |= 1ull << s;
            }
        }
        for (int i = 0; i < 500; i++) {
            u64 kwi = __shfl(kw, i >> 6);
            if ((kwi >> (i & 63)) & 1ull) {
                u64 m = mlds[i * 16 + (lane & 15)];
                kw &= ~m;
            }
        }
    }
    __syncthreads();
    // stage rows 500..999
    for (int i = tid; i < 8000; i += 256) mlds[i] = mrow[8000 + i];
    __syncthreads();
    if (tid < 64) {
        int lane = tid;
        for (int i = 500; i < 1000; i++) {
            u64 kwi = __shfl(kw, i >> 6);
            if ((kwi >> (i & 63)) & 1ull) {
                u64 m = mlds[(i - 500) * 16 + (lane & 15)];
                kw &= ~m;
            }
        }
        if (lane < 16) keepw[lane] = kw;
    }
    __syncthreads();
    if (tid == 0) {
        int c = 0;
        for (int w = 0; w < 16; w++) { pcnt[w] = c; c += __popcll(keepw[w]); }
        pcnt[16] = c;
    }
    __syncthreads();

    int nk = pcnt[16];
    // kept entries, in slot order, are exactly top_k(fs_all, 300)'s leading entries
    for (int slot = tid; slot < PRE_NMS; slot += 256) {
        u64 kv = keepw[slot >> 6];
        if ((kv >> (slot & 63)) & 1ull) {
            int rank = pcnt[slot >> 6] + __popcll(kv & ((1ull << (slot & 63)) - 1ull));
            if (rank < POST_NMS) {
                ((float4*)out)[img * POST_NMS + rank] =
                    ((const float4*)sel_boxes)[img * PRE_NMS + slot];
                out[NIMG * POST_NMS * 4 + img * POST_NMS + rank] =
                    sel_scores[img * PRE_NMS + slot];
                out[NIMG * POST_NMS * 5 + img * POST_NMS + rank] =
                    (float)sel_labels[img * PRE_NMS + slot];
            }
        }
    }
    // filler slots: box=0, score=-1, label=-1
    for (int r = tid; r < POST_NMS; r += 256) {
        if (r >= nk) {
            ((float4*)out)[img * POST_NMS + r] = make_float4(0.f, 0.f, 0.f, 0.f);
            out[NIMG * POST_NMS * 4 + img * POST_NMS + r] = -1.0f;
            out[NIMG * POST_NMS * 5 + img * POST_NMS + r] = -1.0f;
        }
    }
}

// ---------------------------------------------------------------------------
extern "C" void kernel_launch(void* const* d_in, const int* in_sizes, int n_in,
                              void* d_out, int out_size, void* d_ws, size_t ws_size,
                              hipStream_t stream)
{
    const float* b0 = (const float*)d_in[0];
    const float* s0 = (const float*)d_in[1];
    const float* r0 = (const float*)d_in[2];
    const float* b1 = (const float*)d_in[3];
    const float* s1 = (const float*)d_in[4];
    const float* r1 = (const float*)d_in[5];
    const float* b2 = (const float*)d_in[6];
    const float* s2 = (const float*)d_in[7];
    const float* r2 = (const float*)d_in[8];
    const float* b3 = (const float*)d_in[9];
    const float* s3 = (const float*)d_in[10];
    const float* r3 = (const float*)d_in[11];
    const float* b4 = (const float*)d_in[12];
    const float* s4 = (const float*)d_in[13];
    const float* r4 = (const float*)d_in[14];

    char* ws = (char*)d_ws;
    size_t off = 0;
    float* dec_boxes = (float*)(ws + off); off += (size_t)NIMG * NTOT * 4 * 4;   // 4,190,208
    int*   labels    = (int*)(ws + off);   off += (size_t)NIMG * NTOT * 4;       // 1,047,552
    off = (off + 15) & ~(size_t)15;
    u64* keysA = (u64*)(ws + off); off += (size_t)NIMG * NPAD * 8;               // 2,097,152
    u64* keysB = (u64*)(ws + off); off += (size_t)NIMG * 32768 * 8;              // 1,048,576
    float* sel_boxes  = (float*)(ws + off); off += (size_t)NIMG * PRE_NMS * 4 * 4;
    float* sel_scores = (float*)(ws + off); off += (size_t)NIMG * PRE_NMS * 4;
    int*   sel_labels = (int*)(ws + off);   off += (size_t)NIMG * PRE_NMS * 4;
    u64* mask = (u64*)(ws + off); off += (size_t)NIMG * PRE_NMS * 16 * 8;        // 512,000

    float* out = (float*)d_out;

    k_decode<<<dim3((NIMG * NPAD) / 256), dim3(256), 0, stream>>>(
        b0, s0, r0, b1, s1, r1, b2, s2, r2, b3, s3, r3, b4, s4, r4,
        dec_boxes, labels, keysA);

    k_chunksort<<<dim3(NIMG * 64), dim3(256), 0, stream>>>(keysA);

    // merge ladder: 64 -> 32 -> 16 -> 8 -> 4 -> 2 -> 1 lists per image
    k_merge<<<dim3(NIMG * 32), dim3(256), 0, stream>>>(keysA, keysB, NPAD, 32768, 32);
    k_merge<<<dim3(NIMG * 16), dim3(256), 0, stream>>>(keysB, keysA, 32768, NPAD, 16);
    k_merge<<<dim3(NIMG * 8),  dim3(256), 0, stream>>>(keysA, keysB, NPAD, 32768, 8);
    k_merge<<<dim3(NIMG * 4),  dim3(256), 0, stream>>>(keysB, keysA, 32768, NPAD, 4);
    k_merge<<<dim3(NIMG * 2),  dim3(256), 0, stream>>>(keysA, keysB, NPAD, 32768, 2);
    k_merge<<<dim3(NIMG * 1),  dim3(256), 0, stream>>>(keysB, keysA, 32768, NPAD, 1);

    k_gather<<<dim3(NIMG), dim3(256), 0, stream>>>(keysA, dec_boxes, labels,
                                                   sel_boxes, sel_scores, sel_labels);

    k_mask<<<dim3((NIMG * PRE_NMS * 16) / 256), dim3(256), 0, stream>>>(sel_boxes, mask);

    k_sweep<<<dim3(NIMG), dim3(256), 0, stream>>>(mask, sel_boxes, sel_scores, sel_labels, out);
}

// Round 5
// 299.092 us; speedup vs baseline: 1.1900x; 1.1900x over previous
//
#include <hip/hip_runtime.h>

#define NTOT 65472
#define NPAD 65536
#define NIMG 4
#define PRE_NMS 1000
#define POST_NMS 300

typedef unsigned long long u64;

// ---------------------------------------------------------------------------
// Kernel 1: decode. One thread per (image, padded anchor).
// key = (~orderable(score) << 32) | anchor_idx  -> ascending = score desc, idx asc
// ---------------------------------------------------------------------------
__global__ __launch_bounds__(256) void k_decode(
    const float* __restrict__ b0, const float* __restrict__ s0, const float* __restrict__ r0,
    const float* __restrict__ b1, const float* __restrict__ s1, const float* __restrict__ r1,
    const float* __restrict__ b2, const float* __restrict__ s2, const float* __restrict__ r2,
    const float* __restrict__ b3, const float* __restrict__ s3, const float* __restrict__ r3,
    const float* __restrict__ b4, const float* __restrict__ s4, const float* __restrict__ r4,
    float* __restrict__ dec_boxes, int* __restrict__ labels, u64* __restrict__ keys)
{
    int gid = blockIdx.x * 256 + threadIdx.x;   // 0 .. 4*65536
    int img = gid >> 16;
    int a   = gid & 0xFFFF;
    if (a >= NTOT) { keys[gid] = ~0ull; return; }

    const float *bp, *sp, *rp; int la, nl;
    if (a < 49152)      { bp=b0; sp=s0; rp=r0; la=a;        nl=49152; }
    else if (a < 61440) { bp=b1; sp=s1; rp=r1; la=a-49152;  nl=12288; }
    else if (a < 64512) { bp=b2; sp=s2; rp=r2; la=a-61440;  nl=3072;  }
    else if (a < 65280) { bp=b3; sp=s3; rp=r3; la=a-64512;  nl=768;   }
    else                { bp=b4; sp=s4; rp=r4; la=a-65280;  nl=192;   }

    size_t row = (size_t)img * nl + la;

    // max/argmax over classes 1..79 (class 0 = background, masked to -inf).
    const float4* s4v = (const float4*)(sp + row * 80);
    float best; int lab;
    {
        float4 v = s4v[0];
        best = v.y; lab = 1;
        if (v.z > best) { best = v.z; lab = 2; }
        if (v.w > best) { best = v.w; lab = 3; }
    }
#pragma unroll
    for (int q = 1; q < 20; q++) {
        float4 v = s4v[q];
        int c = q * 4;
        if (v.x > best) { best = v.x; lab = c;     }
        if (v.y > best) { best = v.y; lab = c + 1; }
        if (v.z > best) { best = v.z; lab = c + 2; }
        if (v.w > best) { best = v.w; lab = c + 3; }
    }

    float4 bx = ((const float4*)bp)[row];
    float4 rg = ((const float4*)rp)[row];
    float x1 = bx.x, y1 = bx.y, x2 = bx.z, y2 = bx.w;
    float w = x2 - x1, h = y2 - y1;
    float cx = x1 + 0.5f * w, cy = y1 + 0.5f * h;
    float dx = rg.x * 0.1f, dy = rg.y * 0.1f, dw = rg.z * 0.2f, dh = rg.w * 0.2f;
    float pcx = dx * w + cx, pcy = dy * h + cy;
    float pw = expf(dw) * w, ph = expf(dh) * h;
    float nx1 = pcx - 0.5f * pw, ny1 = pcy - 0.5f * ph;
    float nx2 = pcx + 0.5f * pw, ny2 = pcy + 0.5f * ph;
    nx1 = fminf(fmaxf(nx1, 0.0f), 1024.0f);
    ny1 = fminf(fmaxf(ny1, 0.0f), 1024.0f);
    nx2 = fminf(fmaxf(nx2, 0.0f), 1024.0f);
    ny2 = fminf(fmaxf(ny2, 0.0f), 1024.0f);
    float wc = nx2 - nx1, hc = ny2 - ny1;
    bool valid = (best > 0.05f) && (wc >= 2.0f) && (hc >= 2.0f);
    float ns = valid ? best : -1.0f;

    size_t gi = (size_t)img * NTOT + a;
    ((float4*)dec_boxes)[gi] = make_float4(nx1, ny1, nx2, ny2);
    labels[gi] = lab;

    unsigned u = __float_as_uint(ns);
    unsigned ord = (u & 0x80000000u) ? ~u : (u | 0x80000000u);
    unsigned d = ~ord;
    keys[gid] = ((u64)d << 32) | (unsigned)a;
}

// ---------------------------------------------------------------------------
// Kernel 2: per-1024-chunk bitonic sort (ascending) in LDS.
// ---------------------------------------------------------------------------
__global__ __launch_bounds__(256) void k_chunksort(u64* __restrict__ keys)
{
    __shared__ u64 s[1024];
    u64* base = keys + (size_t)blockIdx.x * 1024;
    for (int i = threadIdx.x; i < 1024; i += 256) s[i] = base[i];
    __syncthreads();
    for (int k = 2; k <= 1024; k <<= 1) {
        for (int j = k >> 1; j > 0; j >>= 1) {
            for (int t = threadIdx.x; t < 1024; t += 256) {
                int l = t ^ j;
                if (l > t) {
                    u64 x = s[t], y = s[l];
                    bool up = (t & k) == 0;
                    if (up ? (x > y) : (x < y)) { s[t] = y; s[l] = x; }
                }
            }
            __syncthreads();
        }
    }
    for (int i = threadIdx.x; i < 1024; i += 256) base[i] = s[i];
}

// ---------------------------------------------------------------------------
// Kernel 3: merge two sorted 1024-lists, keep smallest (best) 1024, sorted.
// ---------------------------------------------------------------------------
__global__ __launch_bounds__(256) void k_merge(const u64* __restrict__ in, u64* __restrict__ out,
                                               int inStride, int outStride, int nOut)
{
    __shared__ u64 s[2048];
    int img = blockIdx.x / nOut;
    int p   = blockIdx.x % nOut;
    const u64* a = in + (size_t)img * inStride + (size_t)(2 * p) * 1024;
    for (int i = threadIdx.x; i < 1024; i += 256) s[i] = a[i];
    for (int i = threadIdx.x; i < 1024; i += 256) s[1024 + i] = a[1024 + (1023 - i)];
    __syncthreads();
    for (int i = threadIdx.x; i < 1024; i += 256) {
        u64 x = s[i], y = s[i + 1024];
        s[i] = (x < y) ? x : y;
    }
    __syncthreads();
    for (int j = 512; j > 0; j >>= 1) {
        for (int t = threadIdx.x; t < 1024; t += 256) {
            int l = t ^ j;
            if (l > t) {
                u64 x = s[t], y = s[l];
                if (x > y) { s[t] = y; s[l] = x; }
            }
        }
        __syncthreads();
    }
    u64* o = out + (size_t)img * outStride + (size_t)p * 1024;
    for (int i = threadIdx.x; i < 1024; i += 256) o[i] = s[i];
}

// ---------------------------------------------------------------------------
// Kernel 4: gather top-1000 (sorted) boxes/scores/labels.
// ---------------------------------------------------------------------------
__global__ __launch_bounds__(256) void k_gather(const u64* __restrict__ keys,
                                                const float* __restrict__ dec_boxes,
                                                const int* __restrict__ labels,
                                                float* __restrict__ sel_boxes,
                                                float* __restrict__ sel_scores,
                                                int* __restrict__ sel_labels)
{
    int img = blockIdx.x;
    const u64* list = keys + (size_t)img * NPAD;
    for (int r = threadIdx.x; r < PRE_NMS; r += 256) {
        u64 k = list[r];
        unsigned d = (unsigned)(k >> 32);
        unsigned idx = (unsigned)(k & 0xFFFFFFFFu);
        unsigned ord = ~d;
        unsigned u = (ord & 0x80000000u) ? (ord ^ 0x80000000u) : ~ord;
        float sc = __uint_as_float(u);
        size_t gi = (size_t)img * NTOT + idx;
        ((float4*)sel_boxes)[img * PRE_NMS + r] = ((const float4*)dec_boxes)[gi];
        sel_scores[img * PRE_NMS + r] = sc;
        sel_labels[img * PRE_NMS + r] = labels[gi];
    }
}

// ---------------------------------------------------------------------------
// Kernel 5: IoU suppression bitmask, TRANSPOSED layout [img][word][row].
// Thread t -> img = t/16000, w = (t%16000)/1000, row = t%1000.
// Writes fully coalesced; inner-loop bb loads are wave-uniform broadcasts.
// bit j of mask_t[img][w][row] = IoU(row, w*64+j) > 0.5 && w*64+j > row.
// ---------------------------------------------------------------------------
__global__ __launch_bounds__(256) void k_mask(const float* __restrict__ sel_boxes,
                                              u64* __restrict__ mask_t)
{
    int t = blockIdx.x * 256 + threadIdx.x;   // 4*16*1000 = 64000
    int img = t / 16000;
    int rem = t % 16000;
    int w   = rem / 1000;
    int row = rem % 1000;
    float4 br = ((const float4*)sel_boxes)[img * PRE_NMS + row];
    float ax1 = br.x, ay1 = br.y, ax2 = br.z, ay2 = br.w;
    float aarea = (ax2 - ax1) * (ay2 - ay1);
    u64 bits = 0;
    int j0 = w * 64;
    for (int jj = 0; jj < 64; jj++) {
        int j = j0 + jj;
        if (j >= PRE_NMS || j <= row) continue;
        float4 bb = ((const float4*)sel_boxes)[img * PRE_NMS + j];
        float ix1 = fmaxf(ax1, bb.x), iy1 = fmaxf(ay1, bb.y);
        float ix2 = fminf(ax2, bb.z), iy2 = fminf(ay2, bb.w);
        float iw = fmaxf(ix2 - ix1, 0.0f), ih = fmaxf(iy2 - iy1, 0.0f);
        float inter = iw * ih;
        float barea = (bb.z - bb.x) * (bb.w - bb.y);
        float uni = fmaxf(aarea + barea - inter, 1e-6f);
        if (inter / uni > 0.5f) bits |= 1ull << jj;
    }
    mask_t[t] = bits;   // t == ((img*16 + w)*1000 + row)
}

// ---------------------------------------------------------------------------
// Kernel 6: block-resolve NMS sweep.
// Wave 0 holds all 16 keep-words REPLICATED in every lane's registers
// (static indices only -> no scratch). Per 64-row block w:
//   step1: lane l applies kept rows b*64+l of resolved blocks b<w to word w
//          (parallel), OR-butterfly across lanes.
//   step2: intra-block serial resolve, 64 unrolled steps of ~3 dependent VALU.
// Mask columns (8KB) double-buffered in LDS; waves 1..3 stage next column.
// ---------------------------------------------------------------------------
__global__ __launch_bounds__(256) void k_sweep(const u64* __restrict__ mask_t,
                                               const float* __restrict__ sel_boxes,
                                               const float* __restrict__ sel_scores,
                                               const int* __restrict__ sel_labels,
                                               float* __restrict__ out)
{
    __shared__ u64 col[2][1024];
    __shared__ u64 keepw[16];
    __shared__ int pcnt[17];
    int img = blockIdx.x;
    int tid = threadIdx.x;
    int lane = tid & 63;
    int wid = tid >> 6;
    const u64* mt = mask_t + (size_t)img * 16000;

    // prologue: stage column 0
    for (int i = tid; i < 1024; i += 256) col[0][i] = (i < PRE_NMS) ? mt[i] : 0ull;

    u64 kw[16];
    if (wid == 0) {
        // init keep bits from score threshold (ballot -> full word in all lanes)
#pragma unroll
        for (int b = 0; b < 16; b++) {
            int slot = b * 64 + lane;
            float sc = (slot < PRE_NMS) ? sel_scores[img * PRE_NMS + slot] : -1.0f;
            kw[b] = __ballot(sc > 0.05f);
        }
    }
    __syncthreads();

#define SWEEP_STEP(W)                                                          \
    {                                                                          \
        if ((W) < 15 && wid != 0) {                                            \
            for (int i = tid - 64; i < 1024; i += 192)                         \
                col[((W) + 1) & 1][i] =                                        \
                    (i < PRE_NMS) ? mt[((W) + 1) * 1000 + i] : 0ull;           \
        }                                                                      \
        if (wid == 0) {                                                        \
            const u64* c = col[(W) & 1];                                       \
            u64 m_intra = c[(W) * 64 + lane];                                  \
            u64 sup = 0;                                                       \
            _Pragma("unroll")                                                  \
            for (int b = 0; b < (W); b++) {                                    \
                u64 mrow = c[b * 64 + lane];                                   \
                u64 sel = 0ull - ((kw[b] >> lane) & 1ull);                     \
                sup |= mrow & sel;                                             \
            }                                                                  \
            _Pragma("unroll")                                                  \
            for (int d = 1; d < 64; d <<= 1) sup |= __shfl_xor(sup, d);        \
            u64 kwv = kw[(W)] & ~sup;                                          \
            u64 ms = __shfl(m_intra, 0);                                       \
            _Pragma("unroll")                                                  \
            for (int s = 0; s < 64; s++) {                                     \
                u64 nxt = (s < 63) ? __shfl(m_intra, s + 1) : 0ull;            \
                u64 sel = 0ull - ((kwv >> s) & 1ull);                          \
                kwv &= ~(ms & sel);                                            \
                ms = nxt;                                                      \
            }                                                                  \
            kw[(W)] = kwv;                                                     \
        }                                                                      \
        __syncthreads();                                                       \
    }

    SWEEP_STEP(0)  SWEEP_STEP(1)  SWEEP_STEP(2)  SWEEP_STEP(3)
    SWEEP_STEP(4)  SWEEP_STEP(5)  SWEEP_STEP(6)  SWEEP_STEP(7)
    SWEEP_STEP(8)  SWEEP_STEP(9)  SWEEP_STEP(10) SWEEP_STEP(11)
    SWEEP_STEP(12) SWEEP_STEP(13) SWEEP_STEP(14) SWEEP_STEP(15)
#undef SWEEP_STEP

    if (tid == 0) {
#pragma unroll
        for (int b = 0; b < 16; b++) keepw[b] = kw[b];
        int c = 0;
#pragma unroll
        for (int b = 0; b < 16; b++) { pcnt[b] = c; c += __popcll(kw[b]); }
        pcnt[16] = c;
    }
    __syncthreads();

    int nk = pcnt[16];
    // kept entries, in slot order, are exactly top_k(fs_all, 300)'s leading entries
    for (int slot = tid; slot < PRE_NMS; slot += 256) {
        u64 kv = keepw[slot >> 6];
        if ((kv >> (slot & 63)) & 1ull) {
            int rank = pcnt[slot >> 6] + __popcll(kv & ((1ull << (slot & 63)) - 1ull));
            if (rank < POST_NMS) {
                ((float4*)out)[img * POST_NMS + rank] =
                    ((const float4*)sel_boxes)[img * PRE_NMS + slot];
                out[NIMG * POST_NMS * 4 + img * POST_NMS + rank] =
                    sel_scores[img * PRE_NMS + slot];
                out[NIMG * POST_NMS * 5 + img * POST_NMS + rank] =
                    (float)sel_labels[img * PRE_NMS + slot];
            }
        }
    }
    // filler slots: box=0, score=-1, label=-1
    for (int r = tid; r < POST_NMS; r += 256) {
        if (r >= nk) {
            ((float4*)out)[img * POST_NMS + r] = make_float4(0.f, 0.f, 0.f, 0.f);
            out[NIMG * POST_NMS * 4 + img * POST_NMS + r] = -1.0f;
            out[NIMG * POST_NMS * 5 + img * POST_NMS + r] = -1.0f;
        }
    }
}

// ---------------------------------------------------------------------------
extern "C" void kernel_launch(void* const* d_in, const int* in_sizes, int n_in,
                              void* d_out, int out_size, void* d_ws, size_t ws_size,
                              hipStream_t stream)
{
    const float* b0 = (const float*)d_in[0];
    const float* s0 = (const float*)d_in[1];
    const float* r0 = (const float*)d_in[2];
    const float* b1 = (const float*)d_in[3];
    const float* s1 = (const float*)d_in[4];
    const float* r1 = (const float*)d_in[5];
    const float* b2 = (const float*)d_in[6];
    const float* s2 = (const float*)d_in[7];
    const float* r2 = (const float*)d_in[8];
    const float* b3 = (const float*)d_in[9];
    const float* s3 = (const float*)d_in[10];
    const float* r3 = (const float*)d_in[11];
    const float* b4 = (const float*)d_in[12];
    const float* s4 = (const float*)d_in[13];
    const float* r4 = (const float*)d_in[14];

    char* ws = (char*)d_ws;
    size_t off = 0;
    float* dec_boxes = (float*)(ws + off); off += (size_t)NIMG * NTOT * 4 * 4;
    int*   labels    = (int*)(ws + off);   off += (size_t)NIMG * NTOT * 4;
    off = (off + 15) & ~(size_t)15;
    u64* keysA = (u64*)(ws + off); off += (size_t)NIMG * NPAD * 8;
    u64* keysB = (u64*)(ws + off); off += (size_t)NIMG * 32768 * 8;
    float* sel_boxes  = (float*)(ws + off); off += (size_t)NIMG * PRE_NMS * 4 * 4;
    float* sel_scores = (float*)(ws + off); off += (size_t)NIMG * PRE_NMS * 4;
    int*   sel_labels = (int*)(ws + off);   off += (size_t)NIMG * PRE_NMS * 4;
    u64* mask_t = (u64*)(ws + off); off += (size_t)NIMG * 16 * PRE_NMS * 8;  // [img][word][row]

    float* out = (float*)d_out;

    k_decode<<<dim3((NIMG * NPAD) / 256), dim3(256), 0, stream>>>(
        b0, s0, r0, b1, s1, r1, b2, s2, r2, b3, s3, r3, b4, s4, r4,
        dec_boxes, labels, keysA);

    k_chunksort<<<dim3(NIMG * 64), dim3(256), 0, stream>>>(keysA);

    // merge ladder: 64 -> 32 -> 16 -> 8 -> 4 -> 2 -> 1 lists per image
    k_merge<<<dim3(NIMG * 32), dim3(256), 0, stream>>>(keysA, keysB, NPAD, 32768, 32);
    k_merge<<<dim3(NIMG * 16), dim3(256), 0, stream>>>(keysB, keysA, 32768, NPAD, 16);
    k_merge<<<dim3(NIMG * 8),  dim3(256), 0, stream>>>(keysA, keysB, NPAD, 32768, 8);
    k_merge<<<dim3(NIMG * 4),  dim3(256), 0, stream>>>(keysB, keysA, 32768, NPAD, 4);
    k_merge<<<dim3(NIMG * 2),  dim3(256), 0, stream>>>(keysA, keysB, NPAD, 32768, 2);
    k_merge<<<dim3(NIMG * 1),  dim3(256), 0, stream>>>(keysB, keysA, 32768, NPAD, 1);

    k_gather<<<dim3(NIMG), dim3(256), 0, stream>>>(keysA, dec_boxes, labels,
                                                   sel_boxes, sel_scores, sel_labels);

    k_mask<<<dim3((NIMG * 16 * PRE_NMS) / 256), dim3(256), 0, stream>>>(sel_boxes, mask_t);

    k_sweep<<<dim3(NIMG), dim3(256), 0, stream>>>(mask_t, sel_boxes, sel_scores, sel_labels, out);
}